// Round 9
// baseline (1298.768 us; speedup 1.0000x reference)
//
#include <hip/hip_runtime.h>
#include <math.h>

// ---------------------------------------------------------------------------
// MultiViewEPSSClassifier forward. N=50000, E=600000, IN=512, H=128, B=64, L=4.
// R2: atomic scatter -> CSR gather.   R3: atomic-free pooling; fused GRU GEMM.
// R4: ggnn_w folded into GRU weights; GRU GEMM -> MFMA bf16.
// R5: parallel classifier; proj/attn MFMA; bcast removed.
// R6: bf16 state pipeline; XCD swizzle.
// R7: swapped-operand MFMA in the GRU GEMM (zero-shuffle epilogue).
// R8: channel-permuted B packing -> contiguous per-lane epilogue stores.
// R9: single-barrier A-tile staging (40 KB LDS).
// R10: CSR gather fused into the GRU GEMM (dur 1535 -> 1340 us).
// R11/R12: split-bf16 hi+lo h state; pipelined gather; fused vLN+fusion
//      (1340 -> 1286 us).
// R13: one 512-thread block per 64-row tile — but (512,6) reg cap => spill.
// R14: (512,4): spill-free, 168 us/dispatch, 1246 us total. Unified reg
//      file full (60 VGPR + 64 AGPR = 124/128) => compiler can't prefetch.
// R15: two tn-passes over the LDS A-tile halve acc to [2][4] (32 AGPR);
//      freed regs spent on ks+1 B-fragment double-buffer (L2 latency hides
//      under MFMA) + early h-half load issue (overlaps gather chain).
//      Pass-0 epilogue stashed in regs; final short8 stores stay full-sector.
// ---------------------------------------------------------------------------

typedef __attribute__((ext_vector_type(8))) short short8;
typedef __attribute__((ext_vector_type(4))) float floatx4;

__device__ __forceinline__ unsigned short f2bf_rtn(float x) {
    unsigned u = __float_as_uint(x);
    return (unsigned short)((u + 0x7FFFu + ((u >> 16) & 1u)) >> 16);
}
__device__ __forceinline__ float bf2f(unsigned short h) {
    return __uint_as_float((unsigned)h << 16);
}
__device__ __forceinline__ float fsig(float x) {
    return __builtin_amdgcn_rcpf(1.0f + __expf(-x));
}
__device__ __forceinline__ float ftanh(float x) {
    return 1.0f - 2.0f * __builtin_amdgcn_rcpf(__expf(2.0f * x) + 1.0f);
}

// types {0,9,10}->0, {1,2,3}->1, {4,5,6}->2, {7,8,11,12}->3 (partition of 0..12)
__device__ __forceinline__ int view_of(int t) {
    return (t >= 1 && t <= 3) ? 1 : (t >= 4 && t <= 6) ? 2
         : ((t == 7) || (t == 8) || (t >= 11)) ? 3 : 0;
}

// ----------------- fp32 GEMM (Wcomb precompute only, tiny) -----------------
template <bool BT, int EPI>
__global__ __launch_bounds__(256, 2) void gemm_k(
    const float* __restrict__ A, const float* __restrict__ Bm,
    const float* __restrict__ bias, float* __restrict__ C,
    int N, int M, int K, long sA, long sB, long sC)
{
    __shared__ float As[32][132];
    __shared__ float Bs[32][132];
    A  += (long)blockIdx.z * sA;
    Bm += (long)blockIdx.z * sB;
    C  += (long)blockIdx.z * sC;
    const int r0 = blockIdx.x * 128;
    const int c0 = blockIdx.y * 128;
    const int tid = threadIdx.x;
    const int tx = tid & 15;
    const int ty = tid >> 4;

    float acc[8][8];
#pragma unroll
    for (int i = 0; i < 8; i++)
#pragma unroll
        for (int j = 0; j < 8; j++) acc[i][j] = 0.0f;

    for (int k0 = 0; k0 < K; k0 += 32) {
        {
            int arow = tid >> 3;
            int akq  = (tid & 7) << 2;
#pragma unroll
            for (int hh = 0; hh < 4; hh++) {
                int r  = arow + hh * 32;
                int gr = r0 + r;
                float4 av = make_float4(0.f, 0.f, 0.f, 0.f);
                if (gr < N) av = *(const float4*)(A + (long)gr * K + k0 + akq);
                As[akq + 0][r] = av.x; As[akq + 1][r] = av.y;
                As[akq + 2][r] = av.z; As[akq + 3][r] = av.w;
            }
        }
        if (BT) {
            int brow = tid >> 3;
            int bkq  = (tid & 7) << 2;
#pragma unroll
            for (int hh = 0; hh < 4; hh++) {
                int r = brow + hh * 32;
                float4 bv = *(const float4*)(Bm + (long)(c0 + r) * K + k0 + bkq);
                Bs[bkq + 0][r] = bv.x; Bs[bkq + 1][r] = bv.y;
                Bs[bkq + 2][r] = bv.z; Bs[bkq + 3][r] = bv.w;
            }
        } else {
            int kk0 = tid >> 5;
            int bmq = (tid & 31) << 2;
#pragma unroll
            for (int hh = 0; hh < 4; hh++) {
                int kk = kk0 + hh * 8;
                float4 bv = *(const float4*)(Bm + (long)(k0 + kk) * M + c0 + bmq);
                *(float4*)&Bs[kk][bmq] = bv;
            }
        }
        __syncthreads();
#pragma unroll
        for (int k = 0; k < 32; k++) {
            float4 a0 = *(const float4*)&As[k][ty << 2];
            float4 a1 = *(const float4*)&As[k][64 + (ty << 2)];
            float4 b0 = *(const float4*)&Bs[k][tx << 2];
            float4 b1 = *(const float4*)&Bs[k][64 + (tx << 2)];
            float av[8] = {a0.x, a0.y, a0.z, a0.w, a1.x, a1.y, a1.z, a1.w};
            float bv[8] = {b0.x, b0.y, b0.z, b0.w, b1.x, b1.y, b1.z, b1.w};
#pragma unroll
            for (int i = 0; i < 8; i++)
#pragma unroll
                for (int j = 0; j < 8; j++) acc[i][j] += av[i] * bv[j];
        }
        __syncthreads();
    }

    float bb[8] = {0, 0, 0, 0, 0, 0, 0, 0};
    if (bias) {
        float4 b0 = *(const float4*)(bias + c0 + (tx << 2));
        float4 b1 = *(const float4*)(bias + c0 + 64 + (tx << 2));
        bb[0] = b0.x; bb[1] = b0.y; bb[2] = b0.z; bb[3] = b0.w;
        bb[4] = b1.x; bb[5] = b1.y; bb[6] = b1.z; bb[7] = b1.w;
    }
#pragma unroll
    for (int i = 0; i < 8; i++) {
        int r = (i < 4) ? (r0 + (ty << 2) + i) : (r0 + 64 + (ty << 2) + i - 4);
        if (r < N) {
            float v[8];
#pragma unroll
            for (int j = 0; j < 8; j++) {
                v[j] = acc[i][j] + bb[j];
                if (EPI == 1) v[j] = tanhf(v[j]);
            }
            *(float4*)(C + (long)r * M + c0 + (tx << 2)) = make_float4(v[0], v[1], v[2], v[3]);
            *(float4*)(C + (long)r * M + c0 + 64 + (tx << 2)) = make_float4(v[4], v[5], v[6], v[7]);
        }
    }
}

// ---------- build P_ih_rep[16][128][512], P_hh[4][128][512], bias ----------
__global__ __launch_bounds__(256) void build_p_k(
    const float* __restrict__ gwih, const float* __restrict__ gwhh,
    const float* __restrict__ gbih, const float* __restrict__ gbhh,
    float* __restrict__ pih, float* __restrict__ phh, float* __restrict__ bp)
{
    int idx = blockIdx.x * 256 + threadIdx.x;
    if (idx < 16 * 65536) {
        int z = idx >> 16, rem = idx & 65535;
        int k = rem >> 9, mcol = rem & 511;
        int ch = mcol >> 2, g = mcol & 3;
        int v = z >> 2;
        const float* Wih = gwih + (long)v * 384 * 128;
        float val = 0.0f;
        if (g == 0) val = Wih[ch * 128 + k];
        else if (g == 1) val = Wih[(128 + ch) * 128 + k];
        else if (g == 2) val = Wih[(256 + ch) * 128 + k];
        pih[idx] = val;
    }
    if (idx < 4 * 65536) {
        int v = idx >> 16, rem = idx & 65535;
        int k = rem >> 9, mcol = rem & 511;
        int ch = mcol >> 2, g = mcol & 3;
        const float* Whh = gwhh + (long)v * 384 * 128;
        float val = 0.0f;
        if (g == 0) val = Whh[ch * 128 + k];
        else if (g == 1) val = Whh[(128 + ch) * 128 + k];
        else if (g == 3) val = Whh[(256 + ch) * 128 + k];
        phh[idx] = val;
    }
    if (idx < 4 * 512) {
        int v = idx >> 9, mcol = idx & 511;
        int ch = mcol >> 2, g = mcol & 3;
        float val;
        if (g == 0) val = gbih[v * 384 + ch] + gbhh[v * 384 + ch];
        else if (g == 1) val = gbih[v * 384 + 128 + ch] + gbhh[v * 384 + 128 + ch];
        else if (g == 2) val = gbih[v * 384 + 256 + ch];
        else val = gbhh[v * 384 + 256 + ch];
        bp[idx] = val;
    }
}

// ---- pack combined GRU weights -> bf16 frag order [z][ks][col][q*8+j] -----
// R8 channel permutation: col = base128 + tn*16 + q*4 + g carries channel
// ch = base128/4 + q*8 + tn, gate g.
__global__ __launch_bounds__(256) void pack_b_k(
    const float* __restrict__ wcomb, const float* __restrict__ phh,
    short* __restrict__ Bp)
{
    int idx = blockIdx.x * 256 + threadIdx.x;
    if (idx >= 16 * 256 * 512) return;
    int z = idx >> 17, rem = idx & 131071;
    int k = rem >> 9, col = rem & 511;
    int g  = col & 3;
    int q  = (col >> 2) & 3;
    int tn = (col >> 4) & 7;
    int ch = ((col >> 7) << 5) + (q << 3) + tn;
    int mcol = (ch << 2) + g;
    float val = (k < 128) ? wcomb[(long)z * 65536 + k * 512 + mcol]
                          : phh[(long)(z >> 2) * 65536 + (k - 128) * 512 + mcol];
    long dst = ((long)(z * 8 + (k >> 5)) * 512 + col) * 32 + ((k >> 3) & 3) * 8 + (k & 7);
    Bp[dst] = (short)f2bf_rtn(val);
}

// ---- pack fp32 weight [K][128] (or transposed [128][K]) -> bf16 hi/lo -----
template <bool BT>
__global__ __launch_bounds__(256) void pack_w_k(
    const float* __restrict__ W, short* __restrict__ bhi, short* __restrict__ blo, int K)
{
    int idx = blockIdx.x * 256 + threadIdx.x;
    if (idx >= K * 128) return;
    int k = idx >> 7, col = idx & 127;
    float v = BT ? W[col * K + k] : W[k * 128 + col];
    unsigned short h = f2bf_rtn(v);
    float fh = __uint_as_float((unsigned)h << 16);
    long dst = ((long)(k >> 5) * 128 + col) * 32 + ((k >> 3) & 3) * 8 + (k & 7);
    bhi[dst] = (short)h;
    blo[dst] = (short)f2bf_rtn(v - fh);
}

// ------------- MFMA GEMM: C[N,128] = A[N,K]@W + bias, 3-pass ---------------
template <int EPI>
__global__ __launch_bounds__(256, 4) void gemm_mfma_k(
    const float* __restrict__ A, const short* __restrict__ Bhi,
    const short* __restrict__ Blo, const float* __restrict__ bias,
    float* __restrict__ C, int N, int K)
{
    __shared__ __align__(16) short Ahi[64 * 40];
    __shared__ __align__(16) short Alo[64 * 40];
    const int r0 = blockIdx.x * 64;
    const int tid = threadIdx.x;
    const int l = tid & 63, w = tid >> 6;
    const int wrow = w * 16;
    const int m = l & 15, q = l >> 4;

    floatx4 acc[8];
#pragma unroll
    for (int b = 0; b < 8; b++) acc[b] = (floatx4)0.0f;

    const int arow = tid >> 2;
    const int fcol = (tid & 3) * 8;
    const int gr = r0 + arow;
    const int nks = K >> 5;

    for (int ks = 0; ks < nks; ks++) {
        float xv[8];
        if (gr < N) {
            float4 x0 = *(const float4*)(A + (long)gr * K + ks * 32 + fcol);
            float4 x1 = *(const float4*)(A + (long)gr * K + ks * 32 + fcol + 4);
            xv[0] = x0.x; xv[1] = x0.y; xv[2] = x0.z; xv[3] = x0.w;
            xv[4] = x1.x; xv[5] = x1.y; xv[6] = x1.z; xv[7] = x1.w;
        } else {
#pragma unroll
            for (int u = 0; u < 8; u++) xv[u] = 0.0f;
        }
        short8 vhi, vlo;
#pragma unroll
        for (int u = 0; u < 8; u++) {
            unsigned short hb = f2bf_rtn(xv[u]);
            float fh = __uint_as_float((unsigned)hb << 16);
            vhi[u] = (short)hb;
            vlo[u] = (short)f2bf_rtn(xv[u] - fh);
        }
        *(short8*)&Ahi[arow * 40 + fcol] = vhi;
        *(short8*)&Alo[arow * 40 + fcol] = vlo;
        __syncthreads();
        short8 ah = *(short8*)&Ahi[(wrow + m) * 40 + q * 8];
        short8 al = *(short8*)&Alo[(wrow + m) * 40 + q * 8];
#pragma unroll
        for (int tn = 0; tn < 8; tn++) {
            int col = tn * 16 + m;
            short8 bh = *(const short8*)(Bhi + ((long)ks * 128 + col) * 32 + q * 8);
            short8 bl = *(const short8*)(Blo + ((long)ks * 128 + col) * 32 + q * 8);
            acc[tn] = __builtin_amdgcn_mfma_f32_16x16x32_bf16(ah, bh, acc[tn], 0, 0, 0);
            acc[tn] = __builtin_amdgcn_mfma_f32_16x16x32_bf16(al, bh, acc[tn], 0, 0, 0);
            acc[tn] = __builtin_amdgcn_mfma_f32_16x16x32_bf16(ah, bl, acc[tn], 0, 0, 0);
        }
        __syncthreads();
    }

#pragma unroll
    for (int tn = 0; tn < 8; tn++) {
        int col = tn * 16 + m;
        float bb = bias ? bias[col] : 0.0f;
#pragma unroll
        for (int reg = 0; reg < 4; reg++) {
            int row = r0 + wrow + q * 4 + reg;
            if (row < N) {
                float v = acc[tn][reg] + bb;
                if (EPI == 1) v = ftanh(v);
                C[(long)row * 128 + col] = v;
            }
        }
    }
}

// ---------- MFMA fused gather+GRU GEMM: h_next = GRU(sum_nbr h, h) ---------
// R13/R14: 512 threads, one block per 64-row tile, all 512 gate-cols.
// R15: MFMA stream runs in TWO tn-passes of 4 over the LDS A-tile:
//   acc[2][4] = 32 AGPR (was 64), freed regs fund an explicit ks+1
//   B-fragment double-buffer (L2 latency hides under the 8 MFMAs of the
//   current ks) and early h-half load issue (overlaps the gather chain).
//   Pass-0 GRU results stash in 8 VGPR; single short8 store per row at the
//   end of pass 1 keeps stores full-sector (R8 invariant).
__global__ __launch_bounds__(512, 4) void gemm_gru_mfma_k(
    const short* __restrict__ hb, const short* __restrict__ hpHi,
    const short* __restrict__ hpLo, const short* __restrict__ Bp,
    const float* __restrict__ bp, short* __restrict__ outHi,
    short* __restrict__ outLo, const int* __restrict__ off,
    const int* __restrict__ esrc, int N, long sV, long sHb, long sHp)
{
    __shared__ __align__(16) short As[8 * 64 * 40];   // 40 KB: 8 ks subtiles
    const int x = blockIdx.x;
    const int z = blockIdx.z;
    const short* hbz = hb + (long)z * sHb;     // h-half source (view z rows)
    const short* hph = hpHi + (long)z * sHp;
    const short* hpl = hpLo + (long)z * sHp;
    Bp  += (long)z * 524288;
    bp  += (long)z * 512;
    outHi += (long)z * sV;
    outLo += (long)z * sV;
    const int r0  = x * 64;
    const int tid = threadIdx.x;
    const int l = tid & 63, w = tid >> 6;              // w in 0..7
    const int wrow = (w & 1) * 32, wcol = (w >> 1) * 128;
    const int m = l & 15, q = l >> 4;

    const int row8 = tid >> 3;       // 0..63: row within tile (8 thr/row)
    const int cg8  = tid & 7;        // 16-channel group
    const int gr = r0 + row8;

    // ---- h-half loads issued EARLY (dense, independent of gather) ----
    short8 h0v = (short8)0, h1v = (short8)0;
    if (gr < N) {
        const short* hp = hbz + (long)gr * 128 + (cg8 << 4);
        h0v = *(const short8*)(hp);
        h1v = *(const short8*)(hp + 8);
    }

    // ---- S-half (subtiles 0..3): CSR gather-sum, 2-deep pipelined ----
    {
        float accS[16];
#pragma unroll
        for (int u = 0; u < 16; u++) accS[u] = 0.0f;
        if (gr < N) {
            const int idx = z * N + gr;
            int j = off[idx];
            const int end = off[idx + 1];
            if (j < end) {
                const short* sp = hb + (long)esrc[j] * 128 + (cg8 << 4);
                short8 p0 = *(const short8*)(sp);
                short8 p1 = *(const short8*)(sp + 8);
                for (; j < end;) {
                    short8 c0 = p0, c1 = p1;
                    ++j;
                    if (j < end) {
                        const short* sq = hb + (long)esrc[j] * 128 + (cg8 << 4);
                        p0 = *(const short8*)(sq);
                        p1 = *(const short8*)(sq + 8);
                    }
#pragma unroll
                    for (int u = 0; u < 8; u++) {
                        accS[u]     += bf2f((unsigned short)c0[u]);
                        accS[8 + u] += bf2f((unsigned short)c1[u]);
                    }
                }
            }
        }
        short8 o0, o1;
#pragma unroll
        for (int u = 0; u < 8; u++) {
            o0[u] = (short)f2bf_rtn(accS[u]);
            o1[u] = (short)f2bf_rtn(accS[8 + u]);
        }
        const int base = (cg8 >> 1) * 2560 + row8 * 40 + (cg8 & 1) * 16;
        *(short8*)&As[base]     = o0;
        *(short8*)&As[base + 8] = o1;
    }

    // ---- h-half (subtiles 4..7): write the early-loaded rows ----
    {
        const int base = (4 + (cg8 >> 1)) * 2560 + row8 * 40 + (cg8 & 1) * 16;
        *(short8*)&As[base]     = h0v;
        *(short8*)&As[base + 8] = h1v;
    }
    __syncthreads();

    // ---- two tn-passes; acc[2][4] (32 AGPR) + B double-buffer ----
    const int chq = (wcol >> 2) + q * 8;
    float hnvS[2][4];   // pass-0 stash

#pragma unroll
    for (int pass = 0; pass < 2; ++pass) {
        const int tnb = pass * 4;
        floatx4 acc[2][4];
#pragma unroll
        for (int a = 0; a < 2; a++)
#pragma unroll
            for (int t = 0; t < 4; t++) acc[a][t] = (floatx4)0.0f;

        short8 bcur[4];
#pragma unroll
        for (int t = 0; t < 4; t++) {
            int col = wcol + (tnb + t) * 16 + m;
            bcur[t] = *(const short8*)(Bp + (long)col * 32 + q * 8);
        }
#pragma unroll
        for (int ks = 0; ks < 8; ks++) {
            short8 bnxt[4];
            if (ks < 7) {
#pragma unroll
                for (int t = 0; t < 4; t++) {
                    int col = wcol + (tnb + t) * 16 + m;
                    bnxt[t] = *(const short8*)(Bp + ((long)(ks + 1) * 512 + col) * 32 + q * 8);
                }
            }
            short8 a0 = *(short8*)&As[ks * 2560 + (wrow + m) * 40 + q * 8];
            short8 a1 = *(short8*)&As[ks * 2560 + (wrow + 16 + m) * 40 + q * 8];
#pragma unroll
            for (int t = 0; t < 4; t++) {
                acc[0][t] = __builtin_amdgcn_mfma_f32_16x16x32_bf16(bcur[t], a0, acc[0][t], 0, 0, 0);
                acc[1][t] = __builtin_amdgcn_mfma_f32_16x16x32_bf16(bcur[t], a1, acc[1][t], 0, 0, 0);
            }
            if (ks < 7) {
#pragma unroll
                for (int t = 0; t < 4; t++) bcur[t] = bnxt[t];
            }
        }

        // ---- GRU epilogue for channels chq+tnb .. chq+tnb+3 ----
        float4 bv[4];
#pragma unroll
        for (int t = 0; t < 4; t++)
            bv[t] = *(const float4*)(bp + (chq + tnb + t) * 4);
#pragma unroll
        for (int a = 0; a < 2; a++) {
            const int row = r0 + wrow + a * 16 + m;
            if (row < N) {
                ushort4 h4 = *(const ushort4*)(hph + (long)row * 128 + chq + tnb);
                ushort4 l4 = *(const ushort4*)(hpl + (long)row * 128 + chq + tnb);
                float hpv[4] = {bf2f(h4.x) + bf2f(l4.x), bf2f(h4.y) + bf2f(l4.y),
                                bf2f(h4.z) + bf2f(l4.z), bf2f(h4.w) + bf2f(l4.w)};
                float hnv[4];
#pragma unroll
                for (int t = 0; t < 4; t++) {
                    floatx4 A = acc[a][t];
                    float rr = fsig(A[0] + bv[t].x);
                    float zz = fsig(A[1] + bv[t].y);
                    float nn = ftanh(A[2] + bv[t].z + rr * (A[3] + bv[t].w));
                    hnv[t] = (1.0f - zz) * nn + zz * hpv[t];
                }
                if (pass == 0) {
#pragma unroll
                    for (int t = 0; t < 4; t++) hnvS[a][t] = hnv[t];
                } else {
                    short8 ohi, olo;
#pragma unroll
                    for (int t = 0; t < 4; t++) {
                        unsigned short hh = f2bf_rtn(hnvS[a][t]);
                        ohi[t] = (short)hh;
                        olo[t] = (short)f2bf_rtn(hnvS[a][t] - bf2f(hh));
                        unsigned short hh2 = f2bf_rtn(hnv[t]);
                        ohi[4 + t] = (short)hh2;
                        olo[4 + t] = (short)f2bf_rtn(hnv[t] - bf2f(hh2));
                    }
                    *(short8*)(outHi + (long)row * 128 + chq) = ohi;
                    *(short8*)(outLo + (long)row * 128 + chq) = olo;
                }
            }
        }
    }
}

// ------- LayerNorm + GELU (in-place) + split-bf16 (hi+lo) copy out ---------
__global__ __launch_bounds__(256) void ln_gelu_k(
    float* __restrict__ h0, short* __restrict__ h0b, short* __restrict__ h0lo,
    const float* __restrict__ w, const float* __restrict__ b, int N)
{
    long t = (long)blockIdx.x * 256 + threadIdx.x;
    int n = (int)(t >> 5), lane = (int)(t & 31);
    if (n >= N) return;
    float* p = h0 + (long)n * 128 + lane * 4;
    float4 x = *(float4*)p;
    float s = x.x + x.y + x.z + x.w;
#pragma unroll
    for (int off = 16; off >= 1; off >>= 1) s += __shfl_xor(s, off);
    float mu = s * (1.0f / 128.0f);
    float4 d = make_float4(x.x - mu, x.y - mu, x.z - mu, x.w - mu);
    float ss = d.x * d.x + d.y * d.y + d.z * d.z + d.w * d.w;
#pragma unroll
    for (int off = 16; off >= 1; off >>= 1) ss += __shfl_xor(ss, off);
    float inv = 1.0f / sqrtf(ss * (1.0f / 128.0f) + 1e-5f);
    float4 wv = *(const float4*)(w + lane * 4);
    float4 bv = *(const float4*)(b + lane * 4);
    float y[4] = {d.x * inv * wv.x + bv.x, d.y * inv * wv.y + bv.y,
                  d.z * inv * wv.z + bv.z, d.w * inv * wv.w + bv.w};
#pragma unroll
    for (int i = 0; i < 4; i++)
        y[i] = 0.5f * y[i] * (1.0f + erff(y[i] * 0.70710678118654752f));
    *(float4*)p = make_float4(y[0], y[1], y[2], y[3]);
    ushort4 hb, lb;
    hb.x = f2bf_rtn(y[0]); lb.x = f2bf_rtn(y[0] - bf2f(hb.x));
    hb.y = f2bf_rtn(y[1]); lb.y = f2bf_rtn(y[1] - bf2f(hb.y));
    hb.z = f2bf_rtn(y[2]); lb.z = f2bf_rtn(y[2] - bf2f(hb.z));
    hb.w = f2bf_rtn(y[3]); lb.w = f2bf_rtn(y[3] - bf2f(hb.w));
    *(ushort4*)(h0b + (long)n * 128 + lane * 4) = hb;
    *(ushort4*)(h0lo + (long)n * 128 + lane * 4) = lb;
}

// ------------------------------ CSR build ----------------------------------
__global__ __launch_bounds__(256) void count_k(
    const int* __restrict__ dst, const int* __restrict__ et,
    int* __restrict__ cnt, int E, int N)
{
    int e = blockIdx.x * 256 + threadIdx.x;
    if (e >= E) return;
    int v = view_of(et[e]);
    atomicAdd(&cnt[v * N + dst[e]], 1);
}

__global__ __launch_bounds__(256) void scan1_k(
    const int* __restrict__ cnt, int* __restrict__ off, int* __restrict__ bsum, int n)
{
    __shared__ int sm[256];
    int base = blockIdx.x * 1024;
    int tid = threadIdx.x;
    int v[4]; int s = 0;
#pragma unroll
    for (int i = 0; i < 4; i++) {
        int idx = base + tid * 4 + i;
        v[i] = (idx < n) ? cnt[idx] : 0; s += v[i];
    }
    sm[tid] = s; __syncthreads();
    for (int o = 1; o < 256; o <<= 1) {
        int t2 = (tid >= o) ? sm[tid - o] : 0;
        __syncthreads(); sm[tid] += t2; __syncthreads();
    }
    int run = sm[tid] - s;
    if (tid == 255) bsum[blockIdx.x] = sm[255];
#pragma unroll
    for (int i = 0; i < 4; i++) {
        int idx = base + tid * 4 + i;
        if (idx < n) off[idx] = run;
        run += v[i];
    }
}

__global__ __launch_bounds__(256) void scan2_k(int* __restrict__ bsum, int nb)
{
    __shared__ int sm[256];
    int tid = threadIdx.x;
    int v = (tid < nb) ? bsum[tid] : 0;
    sm[tid] = v; __syncthreads();
    for (int o = 1; o < 256; o <<= 1) {
        int t2 = (tid >= o) ? sm[tid - o] : 0;
        __syncthreads(); sm[tid] += t2; __syncthreads();
    }
    if (tid < nb) bsum[tid] = sm[tid] - v;
}

__global__ __launch_bounds__(256) void scan3_k(
    int* __restrict__ off, int* __restrict__ cursor,
    const int* __restrict__ bsum, int n, int total)
{
    int i = blockIdx.x * 256 + threadIdx.x;
    if (i < n) {
        int o = off[i] + bsum[i >> 10];
        off[i] = o; cursor[i] = o;
    }
    if (i == 0) off[n] = total;
}

__global__ __launch_bounds__(256) void fill_k(
    const int* __restrict__ src, const int* __restrict__ dst,
    const int* __restrict__ et, int* __restrict__ cursor,
    int* __restrict__ esrc, int* __restrict__ esrc0, int E, int N)
{
    int e = blockIdx.x * 256 + threadIdx.x;
    if (e >= E) return;
    int v = view_of(et[e]);
    int b = v * N + dst[e];
    int pos = atomicAdd(&cursor[b], 1);
    esrc[pos] = v * N + src[e];
    esrc0[pos] = src[e];
}

// ------ fused per-view LayerNorm+residual + attention fusion (R11d) --------
// hs_v = LN(hi_v+lo_v)*w_v+b_v + h0;  lg_v = hs_v . u + q . k_b;
// attn = softmax(lg*scale); fused = sum_v attn_v * hs_v.
__global__ __launch_bounds__(256) void fusion_k(
    const short* __restrict__ hi, const short* __restrict__ lo,
    const float* __restrict__ h0, const float* __restrict__ q,
    const float* __restrict__ u, const float* __restrict__ kb,
    const float* __restrict__ vw, const float* __restrict__ vb,
    float* __restrict__ fused, int N)
{
    long t = (long)blockIdx.x * 256 + threadIdx.x;
    int n = (int)(t >> 5), lane = (int)(t & 31);
    if (n >= N) return;
    float4 qv = *(const float4*)(q + (long)n * 128 + lane * 4);
    float4 kv = *(const float4*)(kb + lane * 4);
    float4 uv = *(const float4*)(u + (long)n * 128 + lane * 4);
    float4 h0v = *(const float4*)(h0 + (long)n * 128 + lane * 4);
    float part = qv.x * kv.x + qv.y * kv.y + qv.z * kv.z + qv.w * kv.w;
    float hs[4][4];
    float lg[4];
#pragma unroll
    for (int v = 0; v < 4; v++) {
        long base = ((long)v * N + n) * 128 + lane * 4;
        ushort4 hu = *(const ushort4*)(hi + base);
        ushort4 lu = *(const ushort4*)(lo + base);
        float hv0 = bf2f(hu.x) + bf2f(lu.x);
        float hv1 = bf2f(hu.y) + bf2f(lu.y);
        float hv2 = bf2f(hu.z) + bf2f(lu.z);
        float hv3 = bf2f(hu.w) + bf2f(lu.w);
        float s = hv0 + hv1 + hv2 + hv3;
#pragma unroll
        for (int off = 16; off >= 1; off >>= 1) s += __shfl_xor(s, off);
        float mu = s * (1.0f / 128.0f);
        float d0 = hv0 - mu, d1 = hv1 - mu, d2 = hv2 - mu, d3 = hv3 - mu;
        float ss = d0 * d0 + d1 * d1 + d2 * d2 + d3 * d3;
#pragma unroll
        for (int off = 16; off >= 1; off >>= 1) ss += __shfl_xor(ss, off);
        float inv = 1.0f / sqrtf(ss * (1.0f / 128.0f) + 1e-5f);
        float4 wv = *(const float4*)(vw + v * 128 + lane * 4);
        float4 bv = *(const float4*)(vb + v * 128 + lane * 4);
        hs[v][0] = d0 * inv * wv.x + bv.x + h0v.x;
        hs[v][1] = d1 * inv * wv.y + bv.y + h0v.y;
        hs[v][2] = d2 * inv * wv.z + bv.z + h0v.z;
        hs[v][3] = d3 * inv * wv.w + bv.w + h0v.w;
        lg[v] = hs[v][0] * uv.x + hs[v][1] * uv.y + hs[v][2] * uv.z + hs[v][3] * uv.w;
    }
#pragma unroll
    for (int off = 16; off >= 1; off >>= 1) {
        part += __shfl_xor(part, off);
#pragma unroll
        for (int v = 0; v < 4; v++) lg[v] += __shfl_xor(lg[v], off);
    }
    const float scale = 0.08838834764831845f;
    float mx = -1e30f;
#pragma unroll
    for (int v = 0; v < 4; v++) { lg[v] = (lg[v] + part) * scale; mx = fmaxf(mx, lg[v]); }
    float se = 0.0f;
#pragma unroll
    for (int v = 0; v < 4; v++) { lg[v] = expf(lg[v] - mx); se += lg[v]; }
    float inv = 1.0f / se;
    float4 f = make_float4(0.f, 0.f, 0.f, 0.f);
#pragma unroll
    for (int v = 0; v < 4; v++) {
        float a = lg[v] * inv;
        f.x += a * hs[v][0]; f.y += a * hs[v][1];
        f.z += a * hs[v][2]; f.w += a * hs[v][3];
    }
    *(float4*)(fused + (long)n * 128 + lane * 4) = f;
}

// ------------- pooling: one block per graph (batch is sorted) --------------
__global__ __launch_bounds__(256) void pool_k(
    const float* __restrict__ fused, const int* __restrict__ batch,
    float* __restrict__ meanb, float* __restrict__ maxb, int N)
{
    __shared__ float s_sum[256], s_max[256];
    int b = blockIdx.x;
    int lo = 0, hi = N;
    while (lo < hi) { int mid = (lo + hi) >> 1; if (batch[mid] < b) lo = mid + 1; else hi = mid; }
    int beg = lo;
    lo = beg; hi = N;
    while (lo < hi) { int mid = (lo + hi) >> 1; if (batch[mid] < b + 1) lo = mid + 1; else hi = mid; }
    int end = lo;
    int tid = threadIdx.x;
    int c = tid & 127, half = tid >> 7;
    float sum = 0.0f, mx = __int_as_float(0xff800000);
    for (int n = beg + half; n < end; n += 2) {
        float v = fused[(long)n * 128 + c];
        sum += v; mx = fmaxf(mx, v);
    }
    s_sum[tid] = sum; s_max[tid] = mx;
    __syncthreads();
    if (half == 0) {
        float tot = s_sum[tid] + s_sum[tid + 128];
        float m2 = fmaxf(s_max[tid], s_max[tid + 128]);
        int cnt = end - beg;
        meanb[b * 128 + c] = tot / (float)max(cnt, 1);
        maxb[b * 128 + c] = m2;
    }
}

// ---------------- classifier MLP: one block per graph (64 blocks) ----------
__global__ __launch_bounds__(256) void classifier_k(
    const float* __restrict__ meanb, const float* __restrict__ maxb,
    const float* __restrict__ c1w, const float* __restrict__ c1b,
    const float* __restrict__ c2w, const float* __restrict__ c2b,
    const float* __restrict__ c3w, const float* __restrict__ c3b,
    float* __restrict__ out)
{
    __shared__ float g[256];
    __shared__ float h1[128];
    __shared__ float h2[64];
    int b = blockIdx.x, tid = threadIdx.x;
    g[tid] = (tid < 128) ? meanb[b * 128 + tid] : maxb[b * 128 + (tid - 128)];
    __syncthreads();
    if (tid < 128) {
        float acc = c1b[tid];
        for (int k = 0; k < 256; k++) acc += g[k] * c1w[k * 128 + tid];
        h1[tid] = fmaxf(acc, 0.0f);
    }
    __syncthreads();
    if (tid < 64) {
        float acc = c2b[tid];
        for (int k = 0; k < 128; k++) acc += h1[k] * c2w[k * 64 + tid];
        h2[tid] = fmaxf(acc, 0.0f);
    }
    __syncthreads();
    if (tid < 64) {
        float p = h2[tid] * c3w[tid];
#pragma unroll
        for (int off = 32; off >= 1; off >>= 1) p += __shfl_xor(p, off);
        if (tid == 0) out[b] = c3b[0] + p;
    }
}

// ---------------------------------------------------------------------------
extern "C" void kernel_launch(void* const* d_in, const int* in_sizes, int n_in,
                              void* d_out, int out_size, void* d_ws, size_t ws_size,
                              hipStream_t stream) {
    (void)n_in; (void)out_size; (void)ws_size;
    const float* x      = (const float*)d_in[0];
    const int*   eidx   = (const int*)d_in[1];
    const int*   etype  = (const int*)d_in[2];
    const int*   batch  = (const int*)d_in[3];
    const float* proj_w = (const float*)d_in[4];
    const float* proj_b = (const float*)d_in[5];
    const float* ln0_w  = (const float*)d_in[6];
    const float* ln0_b  = (const float*)d_in[7];
    const float* ggnn_w = (const float*)d_in[8];
    const float* gwih   = (const float*)d_in[9];
    const float* gwhh   = (const float*)d_in[10];
    const float* gbih   = (const float*)d_in[11];
    const float* gbhh   = (const float*)d_in[12];
    const float* vln_w  = (const float*)d_in[13];
    const float* vln_b  = (const float*)d_in[14];
    const float* q_w    = (const float*)d_in[15];
    const float* q_b    = (const float*)d_in[16];
    const float* k_w    = (const float*)d_in[17];
    const float* k_b    = (const float*)d_in[18];
    const float* c1w    = (const float*)d_in[19];
    const float* c1b    = (const float*)d_in[20];
    const float* c2w    = (const float*)d_in[21];
    const float* c2b    = (const float*)d_in[22];
    const float* c3w    = (const float*)d_in[23];
    const float* c3b    = (const float*)d_in[24];
    float* out = (float*)d_out;

    const int N = in_sizes[3];
    const int E = in_sizes[2];
    const int IN = in_sizes[0] / N;
    const int H = 128, L = 4;
    const int N4 = 4 * N;

    long NH = (long)N * H;
    float* ws = (float*)d_ws;
    float* h0 = ws;                      // NH floats (fp32 h0)
    float* hfz = h0 + NH;                // 4*NH floats: dead fp32 region ->
    short* loA = (short*)hfz;            //   loA: 4*NH shorts
    short* loB = loA + 4 * NH;           //   loB: 4*NH shorts (fills hfz)
    float* poolMean = hfz + 4 * NH;      // 8192
    float* poolMax  = poolMean + 8192;   // 8192
    float* bp = poolMax + 8192;          // 2048
    short* h0b = (short*)(bp + 2048);    // NH  (hi of h0)
    short* hiA = h0b + NH;               // 4*NH
    short* hiB = hiA + 4 * NH;           // 4*NH
    short* Sb  = hiB + 4 * NH;           // 4*NH (qbuf/ubuf overlay)
    short* Bp  = Sb + 4 * NH;            // 16*131072
    short* prjHi = Bp + 16 * 131072;     // 512*128
    short* prjLo = prjHi + 65536;
    short* qwHi  = prjLo + 65536;        // 128*128
    short* qwLo  = qwHi + 16384;
    short* kwHi  = qwLo + 16384;
    short* kwLo  = kwHi + 16384;
    int* iOff  = (int*)(kwLo + 16384);   // N4+1
    int* iCnt  = iOff + N4 + 1;
    int* iCur  = iCnt + N4;
    int* iBsum = iCur + N4;              // 256
    int* iEsrc  = iBsum + 256;           // E
    int* iEsrc0 = iEsrc + E;             // E
    // precompute overlays on hfz (dead before GRU L0 writes loA)
    float* wcomb = hfz;                  // 16*65536
    float* pih   = hfz + 16 * 65536;     // 16*65536
    float* phh   = pih + 16 * 65536;     // 4*65536
    // lo of h0 lives in loB (dead until L1 writes loB; beyond overlays)
    short* lo0 = loB;
    // tail overlays (dead after last GRU / fusion)
    float* qbuf  = (float*)Sb;           // NH
    float* ubuf  = qbuf + NH;            // NH
    float* fused = (float*)hiA;          // NH (hiA dead after L3 input read)

    int rb = (int)(((long)N * 32 + 255) / 256);
    int eb = (E + 255) / 256;
    int nbScan = (N4 + 1023) / 1024;
    int gx64 = (N + 63) / 64;

    const int* esrc_in = eidx;
    const int* edst_in = eidx + E;

    // ---- CSR build ----
    hipMemsetAsync(iCnt, 0, (size_t)N4 * sizeof(int), stream);
    count_k<<<eb, 256, 0, stream>>>(edst_in, etype, iCnt, E, N);
    scan1_k<<<nbScan, 256, 0, stream>>>(iCnt, iOff, iBsum, N4);
    scan2_k<<<1, 256, 0, stream>>>(iBsum, nbScan);
    scan3_k<<<(N4 + 255) / 256, 256, 0, stream>>>(iOff, iCur, iBsum, N4, E);
    fill_k<<<eb, 256, 0, stream>>>(esrc_in, edst_in, etype, iCur, iEsrc, iEsrc0, E, N);

    // ---- GRU weight fold + bf16 packs (once per call) ----
    build_p_k<<<(16 * 65536 + 255) / 256, 256, 0, stream>>>(
        gwih, gwhh, gbih, gbhh, pih, phh, bp);
    gemm_k<false, 0><<<dim3(1, 4, 16), 256, 0, stream>>>(
        ggnn_w, pih, nullptr, wcomb, 128, 512, 128,
        (long)H * H, 65536, 65536);
    pack_b_k<<<(16 * 256 * 512 + 255) / 256, 256, 0, stream>>>(wcomb, phh, Bp);
    pack_w_k<false><<<(IN * 128 + 255) / 256, 256, 0, stream>>>(proj_w, prjHi, prjLo, IN);
    pack_w_k<false><<<(128 * 128 + 255) / 256, 256, 0, stream>>>(q_w, qwHi, qwLo, 128);
    pack_w_k<true><<<(128 * 128 + 255) / 256, 256, 0, stream>>>(k_w, kwHi, kwLo, 128);

    // ---- input projection (MFMA 3-pass) + LN + GELU (+hi/lo copy) ----
    gemm_mfma_k<0><<<gx64, 256, 0, stream>>>(x, prjHi, prjLo, proj_b, h0, N, IN);
    ln_gelu_k<<<rb, 256, 0, stream>>>(h0, h0b, lo0, ln0_w, ln0_b, N);

    // ---- 4 GGNN layers: fused CSR-gather + MFMA GRU (512-thr blocks) ----
    const short* hin = h0b;  long sHb = 0;
    const short* hpH = h0b;  const short* hpL = lo0;  long sHp = 0;
    short* oHi = hiA; short* oLo = loA;
    for (int i = 0; i < L; i++) {
        const int* es = (i == 0) ? iEsrc0 : iEsrc;
        gemm_gru_mfma_k<<<dim3(gx64, 1, 4), 512, 0, stream>>>(
            hin, hpH, hpL, Bp + (long)i * 131072, bp, oHi, oLo, iOff, es,
            N, NH, sHb, sHp);
        hpH = oHi; hpL = oLo; sHp = NH;
        hin = oHi; sHb = NH;
        if (oHi == hiA) { oHi = hiB; oLo = loB; }
        else            { oHi = hiA; oLo = loA; }
    }
    // final state: hiB + loB

    // ---- attention (MFMA) + fused vLN/residual/attention + pool + MLP ----
    gemm_mfma_k<1><<<gx64, 256, 0, stream>>>(h0, qwHi, qwLo, q_b, qbuf, N, 128);
    gemm_mfma_k<0><<<gx64, 256, 0, stream>>>(qbuf, kwHi, kwLo, nullptr, ubuf, N, 128);
    fusion_k<<<rb, 256, 0, stream>>>(hiB, loB, h0, qbuf, ubuf, k_b,
                                     vln_w, vln_b, fused, N);
    pool_k<<<64, 256, 0, stream>>>(fused, batch, poolMean, poolMax, N);
    classifier_k<<<64, 256, 0, stream>>>(
        poolMean, poolMax, c1w, c1b, c2w, c2b, c3w, c3b, out);
}

// Round 10
// 1223.907 us; speedup vs baseline: 1.0612x; 1.0612x over previous
//
#include <hip/hip_runtime.h>
#include <math.h>

// ---------------------------------------------------------------------------
// MultiViewEPSSClassifier forward. N=50000, E=600000, IN=512, H=128, B=64, L=4.
// R2..R12: see history. R13: 512-thr/tile GRU but reg-capped => spill.
// R14: (512,4) spill-free GRU, 168 us/dispatch, total 1246 us (best).
// R15: two-pass acc + B dbuf REGRESSED (182 us: 2x LDS reads, no prefetch
//      materialized). GRU is at its structural floor -> reverted to R14.
// R16: tail work: (a) pack_b_k re-indexed dst-linear (was ~32x write
//      amplification from 2B stores at 64B stride); (b) LN+GELU+hi/lo split
//      fused into the proj GEMM epilogue (deletes ln_gelu_k's 77 MB
//      round-trip; LN reduces via 8 local adds + 4 shfl_xor per row).
// ---------------------------------------------------------------------------

typedef __attribute__((ext_vector_type(8))) short short8;
typedef __attribute__((ext_vector_type(4))) float floatx4;

__device__ __forceinline__ unsigned short f2bf_rtn(float x) {
    unsigned u = __float_as_uint(x);
    return (unsigned short)((u + 0x7FFFu + ((u >> 16) & 1u)) >> 16);
}
__device__ __forceinline__ float bf2f(unsigned short h) {
    return __uint_as_float((unsigned)h << 16);
}
__device__ __forceinline__ float fsig(float x) {
    return __builtin_amdgcn_rcpf(1.0f + __expf(-x));
}
__device__ __forceinline__ float ftanh(float x) {
    return 1.0f - 2.0f * __builtin_amdgcn_rcpf(__expf(2.0f * x) + 1.0f);
}

// types {0,9,10}->0, {1,2,3}->1, {4,5,6}->2, {7,8,11,12}->3 (partition of 0..12)
__device__ __forceinline__ int view_of(int t) {
    return (t >= 1 && t <= 3) ? 1 : (t >= 4 && t <= 6) ? 2
         : ((t == 7) || (t == 8) || (t >= 11)) ? 3 : 0;
}

// ----------------- fp32 GEMM (Wcomb precompute only, tiny) -----------------
template <bool BT, int EPI>
__global__ __launch_bounds__(256, 2) void gemm_k(
    const float* __restrict__ A, const float* __restrict__ Bm,
    const float* __restrict__ bias, float* __restrict__ C,
    int N, int M, int K, long sA, long sB, long sC)
{
    __shared__ float As[32][132];
    __shared__ float Bs[32][132];
    A  += (long)blockIdx.z * sA;
    Bm += (long)blockIdx.z * sB;
    C  += (long)blockIdx.z * sC;
    const int r0 = blockIdx.x * 128;
    const int c0 = blockIdx.y * 128;
    const int tid = threadIdx.x;
    const int tx = tid & 15;
    const int ty = tid >> 4;

    float acc[8][8];
#pragma unroll
    for (int i = 0; i < 8; i++)
#pragma unroll
        for (int j = 0; j < 8; j++) acc[i][j] = 0.0f;

    for (int k0 = 0; k0 < K; k0 += 32) {
        {
            int arow = tid >> 3;
            int akq  = (tid & 7) << 2;
#pragma unroll
            for (int hh = 0; hh < 4; hh++) {
                int r  = arow + hh * 32;
                int gr = r0 + r;
                float4 av = make_float4(0.f, 0.f, 0.f, 0.f);
                if (gr < N) av = *(const float4*)(A + (long)gr * K + k0 + akq);
                As[akq + 0][r] = av.x; As[akq + 1][r] = av.y;
                As[akq + 2][r] = av.z; As[akq + 3][r] = av.w;
            }
        }
        if (BT) {
            int brow = tid >> 3;
            int bkq  = (tid & 7) << 2;
#pragma unroll
            for (int hh = 0; hh < 4; hh++) {
                int r = brow + hh * 32;
                float4 bv = *(const float4*)(Bm + (long)(c0 + r) * K + k0 + bkq);
                Bs[bkq + 0][r] = bv.x; Bs[bkq + 1][r] = bv.y;
                Bs[bkq + 2][r] = bv.z; Bs[bkq + 3][r] = bv.w;
            }
        } else {
            int kk0 = tid >> 5;
            int bmq = (tid & 31) << 2;
#pragma unroll
            for (int hh = 0; hh < 4; hh++) {
                int kk = kk0 + hh * 8;
                float4 bv = *(const float4*)(Bm + (long)(k0 + kk) * M + c0 + bmq);
                *(float4*)&Bs[kk][bmq] = bv;
            }
        }
        __syncthreads();
#pragma unroll
        for (int k = 0; k < 32; k++) {
            float4 a0 = *(const float4*)&As[k][ty << 2];
            float4 a1 = *(const float4*)&As[k][64 + (ty << 2)];
            float4 b0 = *(const float4*)&Bs[k][tx << 2];
            float4 b1 = *(const float4*)&Bs[k][64 + (tx << 2)];
            float av[8] = {a0.x, a0.y, a0.z, a0.w, a1.x, a1.y, a1.z, a1.w};
            float bv[8] = {b0.x, b0.y, b0.z, b0.w, b1.x, b1.y, b1.z, b1.w};
#pragma unroll
            for (int i = 0; i < 8; i++)
#pragma unroll
                for (int j = 0; j < 8; j++) acc[i][j] += av[i] * bv[j];
        }
        __syncthreads();
    }

    float bb[8] = {0, 0, 0, 0, 0, 0, 0, 0};
    if (bias) {
        float4 b0 = *(const float4*)(bias + c0 + (tx << 2));
        float4 b1 = *(const float4*)(bias + c0 + 64 + (tx << 2));
        bb[0] = b0.x; bb[1] = b0.y; bb[2] = b0.z; bb[3] = b0.w;
        bb[4] = b1.x; bb[5] = b1.y; bb[6] = b1.z; bb[7] = b1.w;
    }
#pragma unroll
    for (int i = 0; i < 8; i++) {
        int r = (i < 4) ? (r0 + (ty << 2) + i) : (r0 + 64 + (ty << 2) + i - 4);
        if (r < N) {
            float v[8];
#pragma unroll
            for (int j = 0; j < 8; j++) {
                v[j] = acc[i][j] + bb[j];
                if (EPI == 1) v[j] = tanhf(v[j]);
            }
            *(float4*)(C + (long)r * M + c0 + (tx << 2)) = make_float4(v[0], v[1], v[2], v[3]);
            *(float4*)(C + (long)r * M + c0 + 64 + (tx << 2)) = make_float4(v[4], v[5], v[6], v[7]);
        }
    }
}

// ---------- build P_ih_rep[16][128][512], P_hh[4][128][512], bias ----------
__global__ __launch_bounds__(256) void build_p_k(
    const float* __restrict__ gwih, const float* __restrict__ gwhh,
    const float* __restrict__ gbih, const float* __restrict__ gbhh,
    float* __restrict__ pih, float* __restrict__ phh, float* __restrict__ bp)
{
    int idx = blockIdx.x * 256 + threadIdx.x;
    if (idx < 16 * 65536) {
        int z = idx >> 16, rem = idx & 65535;
        int k = rem >> 9, mcol = rem & 511;
        int ch = mcol >> 2, g = mcol & 3;
        int v = z >> 2;
        const float* Wih = gwih + (long)v * 384 * 128;
        float val = 0.0f;
        if (g == 0) val = Wih[ch * 128 + k];
        else if (g == 1) val = Wih[(128 + ch) * 128 + k];
        else if (g == 2) val = Wih[(256 + ch) * 128 + k];
        pih[idx] = val;
    }
    if (idx < 4 * 65536) {
        int v = idx >> 16, rem = idx & 65535;
        int k = rem >> 9, mcol = rem & 511;
        int ch = mcol >> 2, g = mcol & 3;
        const float* Whh = gwhh + (long)v * 384 * 128;
        float val = 0.0f;
        if (g == 0) val = Whh[ch * 128 + k];
        else if (g == 1) val = Whh[(128 + ch) * 128 + k];
        else if (g == 3) val = Whh[(256 + ch) * 128 + k];
        phh[idx] = val;
    }
    if (idx < 4 * 512) {
        int v = idx >> 9, mcol = idx & 511;
        int ch = mcol >> 2, g = mcol & 3;
        float val;
        if (g == 0) val = gbih[v * 384 + ch] + gbhh[v * 384 + ch];
        else if (g == 1) val = gbih[v * 384 + 128 + ch] + gbhh[v * 384 + 128 + ch];
        else if (g == 2) val = gbih[v * 384 + 256 + ch];
        else val = gbhh[v * 384 + 256 + ch];
        bp[idx] = val;
    }
}

// ---- pack combined GRU weights -> bf16 frag order, DST-LINEAR (R16a) ------
// thread id == packed offset d; invert d -> (z, ks, col, sub, j), k =
// ks*32+sub*8+j. Writes fully coalesced (was 2B stores at 64B stride).
// R8 channel permutation on col retained: slot col carries channel
// ch = (col/128)*32 + q*8 + tn (q=(col>>2)&3, tn=(col>>4)&7), gate g=col&3.
__global__ __launch_bounds__(256) void pack_b_k(
    const float* __restrict__ wcomb, const float* __restrict__ phh,
    short* __restrict__ Bp)
{
    long d = (long)blockIdx.x * 256 + threadIdx.x;
    if (d >= (long)16 * 256 * 512) return;
    int j   = (int)(d & 7);
    int sub = (int)((d >> 3) & 3);
    int col = (int)((d >> 5) & 511);
    int zk  = (int)(d >> 14);
    int ks  = zk & 7, z = zk >> 3;
    int k = ks * 32 + sub * 8 + j;
    int g  = col & 3;
    int q  = (col >> 2) & 3;
    int tn = (col >> 4) & 7;
    int ch = ((col >> 7) << 5) + (q << 3) + tn;
    int mcol = (ch << 2) + g;
    float val = (k < 128) ? wcomb[(long)z * 65536 + k * 512 + mcol]
                          : phh[(long)(z >> 2) * 65536 + (k - 128) * 512 + mcol];
    Bp[d] = (short)f2bf_rtn(val);
}

// ---- pack fp32 weight [K][128] (or transposed [128][K]) -> bf16 hi/lo -----
template <bool BT>
__global__ __launch_bounds__(256) void pack_w_k(
    const float* __restrict__ W, short* __restrict__ bhi, short* __restrict__ blo, int K)
{
    int idx = blockIdx.x * 256 + threadIdx.x;
    if (idx >= K * 128) return;
    int k = idx >> 7, col = idx & 127;
    float v = BT ? W[col * K + k] : W[k * 128 + col];
    unsigned short h = f2bf_rtn(v);
    float fh = __uint_as_float((unsigned)h << 16);
    long dst = ((long)(k >> 5) * 128 + col) * 32 + ((k >> 3) & 3) * 8 + (k & 7);
    bhi[dst] = (short)h;
    blo[dst] = (short)f2bf_rtn(v - fh);
}

// ------------- MFMA GEMM: C[N,128] = A[N,K]@W + bias, 3-pass ---------------
template <int EPI>
__global__ __launch_bounds__(256, 4) void gemm_mfma_k(
    const float* __restrict__ A, const short* __restrict__ Bhi,
    const short* __restrict__ Blo, const float* __restrict__ bias,
    float* __restrict__ C, int N, int K)
{
    __shared__ __align__(16) short Ahi[64 * 40];
    __shared__ __align__(16) short Alo[64 * 40];
    const int r0 = blockIdx.x * 64;
    const int tid = threadIdx.x;
    const int l = tid & 63, w = tid >> 6;
    const int wrow = w * 16;
    const int m = l & 15, q = l >> 4;

    floatx4 acc[8];
#pragma unroll
    for (int b = 0; b < 8; b++) acc[b] = (floatx4)0.0f;

    const int arow = tid >> 2;
    const int fcol = (tid & 3) * 8;
    const int gr = r0 + arow;
    const int nks = K >> 5;

    for (int ks = 0; ks < nks; ks++) {
        float xv[8];
        if (gr < N) {
            float4 x0 = *(const float4*)(A + (long)gr * K + ks * 32 + fcol);
            float4 x1 = *(const float4*)(A + (long)gr * K + ks * 32 + fcol + 4);
            xv[0] = x0.x; xv[1] = x0.y; xv[2] = x0.z; xv[3] = x0.w;
            xv[4] = x1.x; xv[5] = x1.y; xv[6] = x1.z; xv[7] = x1.w;
        } else {
#pragma unroll
            for (int u = 0; u < 8; u++) xv[u] = 0.0f;
        }
        short8 vhi, vlo;
#pragma unroll
        for (int u = 0; u < 8; u++) {
            unsigned short hb = f2bf_rtn(xv[u]);
            float fh = __uint_as_float((unsigned)hb << 16);
            vhi[u] = (short)hb;
            vlo[u] = (short)f2bf_rtn(xv[u] - fh);
        }
        *(short8*)&Ahi[arow * 40 + fcol] = vhi;
        *(short8*)&Alo[arow * 40 + fcol] = vlo;
        __syncthreads();
        short8 ah = *(short8*)&Ahi[(wrow + m) * 40 + q * 8];
        short8 al = *(short8*)&Alo[(wrow + m) * 40 + q * 8];
#pragma unroll
        for (int tn = 0; tn < 8; tn++) {
            int col = tn * 16 + m;
            short8 bh = *(const short8*)(Bhi + ((long)ks * 128 + col) * 32 + q * 8);
            short8 bl = *(const short8*)(Blo + ((long)ks * 128 + col) * 32 + q * 8);
            acc[tn] = __builtin_amdgcn_mfma_f32_16x16x32_bf16(ah, bh, acc[tn], 0, 0, 0);
            acc[tn] = __builtin_amdgcn_mfma_f32_16x16x32_bf16(al, bh, acc[tn], 0, 0, 0);
            acc[tn] = __builtin_amdgcn_mfma_f32_16x16x32_bf16(ah, bl, acc[tn], 0, 0, 0);
        }
        __syncthreads();
    }

#pragma unroll
    for (int tn = 0; tn < 8; tn++) {
        int col = tn * 16 + m;
        float bb = bias ? bias[col] : 0.0f;
#pragma unroll
        for (int reg = 0; reg < 4; reg++) {
            int row = r0 + wrow + q * 4 + reg;
            if (row < N) {
                float v = acc[tn][reg] + bb;
                if (EPI == 1) v = ftanh(v);
                C[(long)row * 128 + col] = v;
            }
        }
    }
}

// ---- MFMA proj GEMM with fused LayerNorm+GELU+split-bf16 epilogue (R16b) --
// h0 = gelu(LN(x@W+b)); also emits hi=bf16(h0), lo=bf16(h0-hi).
// LN per row: 8 local adds over tn + 4 shfl_xor across the 16-lane m-group
// (lanes q*16+m share q => xor on m-bits stays in-group).
__global__ __launch_bounds__(256, 4) void gemm_proj_ln_k(
    const float* __restrict__ A, const short* __restrict__ Bhi,
    const short* __restrict__ Blo, const float* __restrict__ bias,
    const float* __restrict__ lnw, const float* __restrict__ lnb,
    float* __restrict__ h0, short* __restrict__ h0b, short* __restrict__ h0lo,
    int N, int K)
{
    __shared__ __align__(16) short Ahi[64 * 40];
    __shared__ __align__(16) short Alo[64 * 40];
    const int r0 = blockIdx.x * 64;
    const int tid = threadIdx.x;
    const int l = tid & 63, w = tid >> 6;
    const int wrow = w * 16;
    const int m = l & 15, q = l >> 4;

    floatx4 acc[8];
#pragma unroll
    for (int b = 0; b < 8; b++) acc[b] = (floatx4)0.0f;

    const int arow = tid >> 2;
    const int fcol = (tid & 3) * 8;
    const int gr = r0 + arow;
    const int nks = K >> 5;

    for (int ks = 0; ks < nks; ks++) {
        float xv[8];
        if (gr < N) {
            float4 x0 = *(const float4*)(A + (long)gr * K + ks * 32 + fcol);
            float4 x1 = *(const float4*)(A + (long)gr * K + ks * 32 + fcol + 4);
            xv[0] = x0.x; xv[1] = x0.y; xv[2] = x0.z; xv[3] = x0.w;
            xv[4] = x1.x; xv[5] = x1.y; xv[6] = x1.z; xv[7] = x1.w;
        } else {
#pragma unroll
            for (int u = 0; u < 8; u++) xv[u] = 0.0f;
        }
        short8 vhi, vlo;
#pragma unroll
        for (int u = 0; u < 8; u++) {
            unsigned short hb = f2bf_rtn(xv[u]);
            float fh = __uint_as_float((unsigned)hb << 16);
            vhi[u] = (short)hb;
            vlo[u] = (short)f2bf_rtn(xv[u] - fh);
        }
        *(short8*)&Ahi[arow * 40 + fcol] = vhi;
        *(short8*)&Alo[arow * 40 + fcol] = vlo;
        __syncthreads();
        short8 ah = *(short8*)&Ahi[(wrow + m) * 40 + q * 8];
        short8 al = *(short8*)&Alo[(wrow + m) * 40 + q * 8];
#pragma unroll
        for (int tn = 0; tn < 8; tn++) {
            int col = tn * 16 + m;
            short8 bh = *(const short8*)(Bhi + ((long)ks * 128 + col) * 32 + q * 8);
            short8 bl = *(const short8*)(Blo + ((long)ks * 128 + col) * 32 + q * 8);
            acc[tn] = __builtin_amdgcn_mfma_f32_16x16x32_bf16(ah, bh, acc[tn], 0, 0, 0);
            acc[tn] = __builtin_amdgcn_mfma_f32_16x16x32_bf16(al, bh, acc[tn], 0, 0, 0);
            acc[tn] = __builtin_amdgcn_mfma_f32_16x16x32_bf16(ah, bl, acc[tn], 0, 0, 0);
        }
        __syncthreads();
    }

    float bb[8], lw[8], lb[8];
#pragma unroll
    for (int tn = 0; tn < 8; tn++) {
        int col = tn * 16 + m;
        bb[tn] = bias[col];
        lw[tn] = lnw[col];
        lb[tn] = lnb[col];
    }
#pragma unroll
    for (int reg = 0; reg < 4; reg++) {
        const int row = r0 + wrow + q * 4 + reg;
        float v8[8];
        float s = 0.0f;
#pragma unroll
        for (int tn = 0; tn < 8; tn++) {
            v8[tn] = acc[tn][reg] + bb[tn];
            s += v8[tn];
        }
#pragma unroll
        for (int off = 8; off >= 1; off >>= 1) s += __shfl_xor(s, off);
        float mu = s * (1.0f / 128.0f);
        float ss = 0.0f;
#pragma unroll
        for (int tn = 0; tn < 8; tn++) {
            float d = v8[tn] - mu;
            ss += d * d;
        }
#pragma unroll
        for (int off = 8; off >= 1; off >>= 1) ss += __shfl_xor(ss, off);
        float inv = 1.0f / sqrtf(ss * (1.0f / 128.0f) + 1e-5f);
        if (row < N) {
#pragma unroll
            for (int tn = 0; tn < 8; tn++) {
                int col = tn * 16 + m;
                float y = (v8[tn] - mu) * inv * lw[tn] + lb[tn];
                y = 0.5f * y * (1.0f + erff(y * 0.70710678118654752f));
                h0[(long)row * 128 + col] = y;
                unsigned short hh = f2bf_rtn(y);
                h0b[(long)row * 128 + col] = (short)hh;
                h0lo[(long)row * 128 + col] = (short)f2bf_rtn(y - bf2f(hh));
            }
        }
    }
}

// ---------- MFMA fused gather+GRU GEMM: h_next = GRU(sum_nbr h, h) ---------
// R13/R14 (reverted R15): 512 threads, one block per 64-row tile, all 512
// gate-cols. 8 waves = 2 row-halves (w&1) x 4 col-128-groups (w>>1).
// Gather: 8 threads/row x 16 ch, 2-deep pipeline. Split-bf16 hi+lo h state.
// __launch_bounds__(512,4) = 2 blocks/CU, 128-reg budget — spill-free.
__global__ __launch_bounds__(512, 4) void gemm_gru_mfma_k(
    const short* __restrict__ hb, const short* __restrict__ hpHi,
    const short* __restrict__ hpLo, const short* __restrict__ Bp,
    const float* __restrict__ bp, short* __restrict__ outHi,
    short* __restrict__ outLo, const int* __restrict__ off,
    const int* __restrict__ esrc, int N, long sV, long sHb, long sHp)
{
    __shared__ __align__(16) short As[8 * 64 * 40];   // 40 KB: 8 ks subtiles
    const int x = blockIdx.x;
    const int z = blockIdx.z;
    const short* hbz = hb + (long)z * sHb;     // h-half source (view z rows)
    const short* hph = hpHi + (long)z * sHp;
    const short* hpl = hpLo + (long)z * sHp;
    Bp  += (long)z * 524288;
    bp  += (long)z * 512;
    outHi += (long)z * sV;
    outLo += (long)z * sV;
    const int r0  = x * 64;
    const int tid = threadIdx.x;
    const int l = tid & 63, w = tid >> 6;              // w in 0..7
    const int wrow = (w & 1) * 32, wcol = (w >> 1) * 128;
    const int m = l & 15, q = l >> 4;

    const int row8 = tid >> 3;       // 0..63: row within tile (8 thr/row)
    const int cg8  = tid & 7;        // 16-channel group
    const int gr = r0 + row8;

    // ---- S-half (subtiles 0..3): CSR gather-sum, 2-deep pipelined ----
    {
        float accS[16];
#pragma unroll
        for (int u = 0; u < 16; u++) accS[u] = 0.0f;
        if (gr < N) {
            const int idx = z * N + gr;
            int j = off[idx];
            const int end = off[idx + 1];
            if (j < end) {
                const short* sp = hb + (long)esrc[j] * 128 + (cg8 << 4);
                short8 p0 = *(const short8*)(sp);
                short8 p1 = *(const short8*)(sp + 8);
                for (; j < end;) {
                    short8 c0 = p0, c1 = p1;
                    ++j;
                    if (j < end) {
                        const short* sq = hb + (long)esrc[j] * 128 + (cg8 << 4);
                        p0 = *(const short8*)(sq);
                        p1 = *(const short8*)(sq + 8);
                    }
#pragma unroll
                    for (int u = 0; u < 8; u++) {
                        accS[u]     += bf2f((unsigned short)c0[u]);
                        accS[8 + u] += bf2f((unsigned short)c1[u]);
                    }
                }
            }
        }
        short8 o0, o1;
#pragma unroll
        for (int u = 0; u < 8; u++) {
            o0[u] = (short)f2bf_rtn(accS[u]);
            o1[u] = (short)f2bf_rtn(accS[8 + u]);
        }
        const int base = (cg8 >> 1) * 2560 + row8 * 40 + (cg8 & 1) * 16;
        *(short8*)&As[base]     = o0;
        *(short8*)&As[base + 8] = o1;
    }

    // ---- h-half (subtiles 4..7): direct row loads (16 ch/thread) ----
    {
        short8 h0v = (short8)0, h1v = (short8)0;
        if (gr < N) {
            const short* hp = hbz + (long)gr * 128 + (cg8 << 4);
            h0v = *(const short8*)(hp);
            h1v = *(const short8*)(hp + 8);
        }
        const int base = (4 + (cg8 >> 1)) * 2560 + row8 * 40 + (cg8 & 1) * 16;
        *(short8*)&As[base]     = h0v;
        *(short8*)&As[base + 8] = h1v;
    }
    __syncthreads();

    floatx4 acc[2][8];
#pragma unroll
    for (int a = 0; a < 2; a++)
#pragma unroll
        for (int b = 0; b < 8; b++) acc[a][b] = (floatx4)0.0f;

    // ---- barrier-free MFMA stream: 8 ks x 16 MFMA, B from L2 ----
#pragma unroll
    for (int ks = 0; ks < 8; ks++) {
        short8 bfr[8];
#pragma unroll
        for (int tn = 0; tn < 8; tn++) {
            int col = wcol + tn * 16 + m;
            bfr[tn] = *(const short8*)(Bp + ((long)ks * 512 + col) * 32 + q * 8);
        }
        short8 a0 = *(short8*)&As[ks * 2560 + (wrow + m) * 40 + q * 8];
        short8 a1 = *(short8*)&As[ks * 2560 + (wrow + 16 + m) * 40 + q * 8];
#pragma unroll
        for (int tn = 0; tn < 8; tn++) {
            acc[0][tn] = __builtin_amdgcn_mfma_f32_16x16x32_bf16(bfr[tn], a0, acc[0][tn], 0, 0, 0);
            acc[1][tn] = __builtin_amdgcn_mfma_f32_16x16x32_bf16(bfr[tn], a1, acc[1][tn], 0, 0, 0);
        }
    }

    // ---- GRU epilogue: lane (m,q) holds gates r,z,n,hn of channels
    // chq..chq+7 (chq = wcol/4 + q*8) for rows r0+wrow+{m, 16+m};
    // hp = hi+lo reconstruction.
    const int chq = (wcol >> 2) + q * 8;
#pragma unroll
    for (int a = 0; a < 2; a++) {
        const int row = r0 + wrow + a * 16 + m;
        if (row < N) {
            short8 h8 = *(const short8*)(hph + (long)row * 128 + chq);
            short8 l8 = *(const short8*)(hpl + (long)row * 128 + chq);
            float hnv[8];
            short8 ohi, olo;
#pragma unroll
            for (int tn = 0; tn < 8; tn++) {
                float hp = bf2f((unsigned short)h8[tn]) + bf2f((unsigned short)l8[tn]);
                float4 bv = *(const float4*)(bp + (chq + tn) * 4);
                floatx4 A = acc[a][tn];
                float rr = fsig(A[0] + bv.x);
                float zz = fsig(A[1] + bv.y);
                float nn = ftanh(A[2] + bv.z + rr * (A[3] + bv.w));
                hnv[tn] = (1.0f - zz) * nn + zz * hp;
                unsigned short hh = f2bf_rtn(hnv[tn]);
                ohi[tn] = (short)hh;
                olo[tn] = (short)f2bf_rtn(hnv[tn] - bf2f(hh));
            }
            *(short8*)(outHi + (long)row * 128 + chq) = ohi;
            *(short8*)(outLo + (long)row * 128 + chq) = olo;
        }
    }
}

// ------------------------------ CSR build ----------------------------------
__global__ __launch_bounds__(256) void count_k(
    const int* __restrict__ dst, const int* __restrict__ et,
    int* __restrict__ cnt, int E, int N)
{
    int e = blockIdx.x * 256 + threadIdx.x;
    if (e >= E) return;
    int v = view_of(et[e]);
    atomicAdd(&cnt[v * N + dst[e]], 1);
}

__global__ __launch_bounds__(256) void scan1_k(
    const int* __restrict__ cnt, int* __restrict__ off, int* __restrict__ bsum, int n)
{
    __shared__ int sm[256];
    int base = blockIdx.x * 1024;
    int tid = threadIdx.x;
    int v[4]; int s = 0;
#pragma unroll
    for (int i = 0; i < 4; i++) {
        int idx = base + tid * 4 + i;
        v[i] = (idx < n) ? cnt[idx] : 0; s += v[i];
    }
    sm[tid] = s; __syncthreads();
    for (int o = 1; o < 256; o <<= 1) {
        int t2 = (tid >= o) ? sm[tid - o] : 0;
        __syncthreads(); sm[tid] += t2; __syncthreads();
    }
    int run = sm[tid] - s;
    if (tid == 255) bsum[blockIdx.x] = sm[255];
#pragma unroll
    for (int i = 0; i < 4; i++) {
        int idx = base + tid * 4 + i;
        if (idx < n) off[idx] = run;
        run += v[i];
    }
}

__global__ __launch_bounds__(256) void scan2_k(int* __restrict__ bsum, int nb)
{
    __shared__ int sm[256];
    int tid = threadIdx.x;
    int v = (tid < nb) ? bsum[tid] : 0;
    sm[tid] = v; __syncthreads();
    for (int o = 1; o < 256; o <<= 1) {
        int t2 = (tid >= o) ? sm[tid - o] : 0;
        __syncthreads(); sm[tid] += t2; __syncthreads();
    }
    if (tid < nb) bsum[tid] = sm[tid] - v;
}

__global__ __launch_bounds__(256) void scan3_k(
    int* __restrict__ off, int* __restrict__ cursor,
    const int* __restrict__ bsum, int n, int total)
{
    int i = blockIdx.x * 256 + threadIdx.x;
    if (i < n) {
        int o = off[i] + bsum[i >> 10];
        off[i] = o; cursor[i] = o;
    }
    if (i == 0) off[n] = total;
}

__global__ __launch_bounds__(256) void fill_k(
    const int* __restrict__ src, const int* __restrict__ dst,
    const int* __restrict__ et, int* __restrict__ cursor,
    int* __restrict__ esrc, int* __restrict__ esrc0, int E, int N)
{
    int e = blockIdx.x * 256 + threadIdx.x;
    if (e >= E) return;
    int v = view_of(et[e]);
    int b = v * N + dst[e];
    int pos = atomicAdd(&cursor[b], 1);
    esrc[pos] = v * N + src[e];
    esrc0[pos] = src[e];
}

// ------ fused per-view LayerNorm+residual + attention fusion (R11d) --------
// hs_v = LN(hi_v+lo_v)*w_v+b_v + h0;  lg_v = hs_v . u + q . k_b;
// attn = softmax(lg*scale); fused = sum_v attn_v * hs_v.
__global__ __launch_bounds__(256) void fusion_k(
    const short* __restrict__ hi, const short* __restrict__ lo,
    const float* __restrict__ h0, const float* __restrict__ q,
    const float* __restrict__ u, const float* __restrict__ kb,
    const float* __restrict__ vw, const float* __restrict__ vb,
    float* __restrict__ fused, int N)
{
    long t = (long)blockIdx.x * 256 + threadIdx.x;
    int n = (int)(t >> 5), lane = (int)(t & 31);
    if (n >= N) return;
    float4 qv = *(const float4*)(q + (long)n * 128 + lane * 4);
    float4 kv = *(const float4*)(kb + lane * 4);
    float4 uv = *(const float4*)(u + (long)n * 128 + lane * 4);
    float4 h0v = *(const float4*)(h0 + (long)n * 128 + lane * 4);
    float part = qv.x * kv.x + qv.y * kv.y + qv.z * kv.z + qv.w * kv.w;
    float hs[4][4];
    float lg[4];
#pragma unroll
    for (int v = 0; v < 4; v++) {
        long base = ((long)v * N + n) * 128 + lane * 4;
        ushort4 hu = *(const ushort4*)(hi + base);
        ushort4 lu = *(const ushort4*)(lo + base);
        float hv0 = bf2f(hu.x) + bf2f(lu.x);
        float hv1 = bf2f(hu.y) + bf2f(lu.y);
        float hv2 = bf2f(hu.z) + bf2f(lu.z);
        float hv3 = bf2f(hu.w) + bf2f(lu.w);
        float s = hv0 + hv1 + hv2 + hv3;
#pragma unroll
        for (int off = 16; off >= 1; off >>= 1) s += __shfl_xor(s, off);
        float mu = s * (1.0f / 128.0f);
        float d0 = hv0 - mu, d1 = hv1 - mu, d2 = hv2 - mu, d3 = hv3 - mu;
        float ss = d0 * d0 + d1 * d1 + d2 * d2 + d3 * d3;
#pragma unroll
        for (int off = 16; off >= 1; off >>= 1) ss += __shfl_xor(ss, off);
        float inv = 1.0f / sqrtf(ss * (1.0f / 128.0f) + 1e-5f);
        float4 wv = *(const float4*)(vw + v * 128 + lane * 4);
        float4 bv = *(const float4*)(vb + v * 128 + lane * 4);
        hs[v][0] = d0 * inv * wv.x + bv.x + h0v.x;
        hs[v][1] = d1 * inv * wv.y + bv.y + h0v.y;
        hs[v][2] = d2 * inv * wv.z + bv.z + h0v.z;
        hs[v][3] = d3 * inv * wv.w + bv.w + h0v.w;
        lg[v] = hs[v][0] * uv.x + hs[v][1] * uv.y + hs[v][2] * uv.z + hs[v][3] * uv.w;
    }
#pragma unroll
    for (int off = 16; off >= 1; off >>= 1) {
        part += __shfl_xor(part, off);
#pragma unroll
        for (int v = 0; v < 4; v++) lg[v] += __shfl_xor(lg[v], off);
    }
    const float scale = 0.08838834764831845f;
    float mx = -1e30f;
#pragma unroll
    for (int v = 0; v < 4; v++) { lg[v] = (lg[v] + part) * scale; mx = fmaxf(mx, lg[v]); }
    float se = 0.0f;
#pragma unroll
    for (int v = 0; v < 4; v++) { lg[v] = expf(lg[v] - mx); se += lg[v]; }
    float inv = 1.0f / se;
    float4 f = make_float4(0.f, 0.f, 0.f, 0.f);
#pragma unroll
    for (int v = 0; v < 4; v++) {
        float a = lg[v] * inv;
        f.x += a * hs[v][0]; f.y += a * hs[v][1];
        f.z += a * hs[v][2]; f.w += a * hs[v][3];
    }
    *(float4*)(fused + (long)n * 128 + lane * 4) = f;
}

// ------------- pooling: one block per graph (batch is sorted) --------------
__global__ __launch_bounds__(256) void pool_k(
    const float* __restrict__ fused, const int* __restrict__ batch,
    float* __restrict__ meanb, float* __restrict__ maxb, int N)
{
    __shared__ float s_sum[256], s_max[256];
    int b = blockIdx.x;
    int lo = 0, hi = N;
    while (lo < hi) { int mid = (lo + hi) >> 1; if (batch[mid] < b) lo = mid + 1; else hi = mid; }
    int beg = lo;
    lo = beg; hi = N;
    while (lo < hi) { int mid = (lo + hi) >> 1; if (batch[mid] < b + 1) lo = mid + 1; else hi = mid; }
    int end = lo;
    int tid = threadIdx.x;
    int c = tid & 127, half = tid >> 7;
    float sum = 0.0f, mx = __int_as_float(0xff800000);
    for (int n = beg + half; n < end; n += 2) {
        float v = fused[(long)n * 128 + c];
        sum += v; mx = fmaxf(mx, v);
    }
    s_sum[tid] = sum; s_max[tid] = mx;
    __syncthreads();
    if (half == 0) {
        float tot = s_sum[tid] + s_sum[tid + 128];
        float m2 = fmaxf(s_max[tid], s_max[tid + 128]);
        int cnt = end - beg;
        meanb[b * 128 + c] = tot / (float)max(cnt, 1);
        maxb[b * 128 + c] = m2;
    }
}

// ---------------- classifier MLP: one block per graph (64 blocks) ----------
__global__ __launch_bounds__(256) void classifier_k(
    const float* __restrict__ meanb, const float* __restrict__ maxb,
    const float* __restrict__ c1w, const float* __restrict__ c1b,
    const float* __restrict__ c2w, const float* __restrict__ c2b,
    const float* __restrict__ c3w, const float* __restrict__ c3b,
    float* __restrict__ out)
{
    __shared__ float g[256];
    __shared__ float h1[128];
    __shared__ float h2[64];
    int b = blockIdx.x, tid = threadIdx.x;
    g[tid] = (tid < 128) ? meanb[b * 128 + tid] : maxb[b * 128 + (tid - 128)];
    __syncthreads();
    if (tid < 128) {
        float acc = c1b[tid];
        for (int k = 0; k < 256; k++) acc += g[k] * c1w[k * 128 + tid];
        h1[tid] = fmaxf(acc, 0.0f);
    }
    __syncthreads();
    if (tid < 64) {
        float acc = c2b[tid];
        for (int k = 0; k < 128; k++) acc += h1[k] * c2w[k * 64 + tid];
        h2[tid] = fmaxf(acc, 0.0f);
    }
    __syncthreads();
    if (tid < 64) {
        float p = h2[tid] * c3w[tid];
#pragma unroll
        for (int off = 32; off >= 1; off >>= 1) p += __shfl_xor(p, off);
        if (tid == 0) out[b] = c3b[0] + p;
    }
}

// ---------------------------------------------------------------------------
extern "C" void kernel_launch(void* const* d_in, const int* in_sizes, int n_in,
                              void* d_out, int out_size, void* d_ws, size_t ws_size,
                              hipStream_t stream) {
    (void)n_in; (void)out_size; (void)ws_size;
    const float* x      = (const float*)d_in[0];
    const int*   eidx   = (const int*)d_in[1];
    const int*   etype  = (const int*)d_in[2];
    const int*   batch  = (const int*)d_in[3];
    const float* proj_w = (const float*)d_in[4];
    const float* proj_b = (const float*)d_in[5];
    const float* ln0_w  = (const float*)d_in[6];
    const float* ln0_b  = (const float*)d_in[7];
    const float* ggnn_w = (const float*)d_in[8];
    const float* gwih   = (const float*)d_in[9];
    const float* gwhh   = (const float*)d_in[10];
    const float* gbih   = (const float*)d_in[11];
    const float* gbhh   = (const float*)d_in[12];
    const float* vln_w  = (const float*)d_in[13];
    const float* vln_b  = (const float*)d_in[14];
    const float* q_w    = (const float*)d_in[15];
    const float* q_b    = (const float*)d_in[16];
    const float* k_w    = (const float*)d_in[17];
    const float* k_b    = (const float*)d_in[18];
    const float* c1w    = (const float*)d_in[19];
    const float* c1b    = (const float*)d_in[20];
    const float* c2w    = (const float*)d_in[21];
    const float* c2b    = (const float*)d_in[22];
    const float* c3w    = (const float*)d_in[23];
    const float* c3b    = (const float*)d_in[24];
    float* out = (float*)d_out;

    const int N = in_sizes[3];
    const int E = in_sizes[2];
    const int IN = in_sizes[0] / N;
    const int H = 128, L = 4;
    const int N4 = 4 * N;

    long NH = (long)N * H;
    float* ws = (float*)d_ws;
    float* h0 = ws;                      // NH floats (fp32 h0)
    float* hfz = h0 + NH;                // 4*NH floats: dead fp32 region ->
    short* loA = (short*)hfz;            //   loA: 4*NH shorts
    short* loB = loA + 4 * NH;           //   loB: 4*NH shorts (fills hfz)
    float* poolMean = hfz + 4 * NH;      // 8192
    float* poolMax  = poolMean + 8192;   // 8192
    float* bp = poolMax + 8192;          // 2048
    short* h0b = (short*)(bp + 2048);    // NH  (hi of h0)
    short* hiA = h0b + NH;               // 4*NH
    short* hiB = hiA + 4 * NH;           // 4*NH
    short* Sb  = hiB + 4 * NH;           // 4*NH (qbuf/ubuf overlay)
    short* Bp  = Sb + 4 * NH;            // 16*131072
    short* prjHi = Bp + 16 * 131072;     // 512*128
    short* prjLo = prjHi + 65536;
    short* qwHi  = prjLo + 65536;        // 128*128
    short* qwLo  = qwHi + 16384;
    short* kwHi  = qwLo + 16384;
    short* kwLo  = kwHi + 16384;
    int* iOff  = (int*)(kwLo + 16384);   // N4+1
    int* iCnt  = iOff + N4 + 1;
    int* iCur  = iCnt + N4;
    int* iBsum = iCur + N4;              // 256
    int* iEsrc  = iBsum + 256;           // E
    int* iEsrc0 = iEsrc + E;             // E
    // precompute overlays on hfz (dead before GRU L0 writes loA)
    float* wcomb = hfz;                  // 16*65536
    float* pih   = hfz + 16 * 65536;     // 16*65536
    float* phh   = pih + 16 * 65536;     // 4*65536
    // lo of h0 lives in loB (dead until L1 writes loB; beyond overlays)
    short* lo0 = loB;
    // tail overlays (dead after last GRU / fusion)
    float* qbuf  = (float*)Sb;           // NH
    float* ubuf  = qbuf + NH;            // NH
    float* fused = (float*)hiA;          // NH (hiA dead after L3 input read)

    int rb = (int)(((long)N * 32 + 255) / 256);
    int eb = (E + 255) / 256;
    int nbScan = (N4 + 1023) / 1024;
    int gx64 = (N + 63) / 64;

    const int* esrc_in = eidx;
    const int* edst_in = eidx + E;

    // ---- CSR build ----
    hipMemsetAsync(iCnt, 0, (size_t)N4 * sizeof(int), stream);
    count_k<<<eb, 256, 0, stream>>>(edst_in, etype, iCnt, E, N);
    scan1_k<<<nbScan, 256, 0, stream>>>(iCnt, iOff, iBsum, N4);
    scan2_k<<<1, 256, 0, stream>>>(iBsum, nbScan);
    scan3_k<<<(N4 + 255) / 256, 256, 0, stream>>>(iOff, iCur, iBsum, N4, E);
    fill_k<<<eb, 256, 0, stream>>>(esrc_in, edst_in, etype, iCur, iEsrc, iEsrc0, E, N);

    // ---- GRU weight fold + bf16 packs (once per call) ----
    build_p_k<<<(16 * 65536 + 255) / 256, 256, 0, stream>>>(
        gwih, gwhh, gbih, gbhh, pih, phh, bp);
    gemm_k<false, 0><<<dim3(1, 4, 16), 256, 0, stream>>>(
        ggnn_w, pih, nullptr, wcomb, 128, 512, 128,
        (long)H * H, 65536, 65536);
    pack_b_k<<<(16 * 256 * 512 + 255) / 256, 256, 0, stream>>>(wcomb, phh, Bp);
    pack_w_k<false><<<(IN * 128 + 255) / 256, 256, 0, stream>>>(proj_w, prjHi, prjLo, IN);
    pack_w_k<false><<<(128 * 128 + 255) / 256, 256, 0, stream>>>(q_w, qwHi, qwLo, 128);
    pack_w_k<true><<<(128 * 128 + 255) / 256, 256, 0, stream>>>(k_w, kwHi, kwLo, 128);

    // ---- input projection with fused LN+GELU+hi/lo (R16b) ----
    gemm_proj_ln_k<<<gx64, 256, 0, stream>>>(
        x, prjHi, prjLo, proj_b, ln0_w, ln0_b, h0, h0b, lo0, N, IN);

    // ---- 4 GGNN layers: fused CSR-gather + MFMA GRU (512-thr blocks) ----
    const short* hin = h0b;  long sHb = 0;
    const short* hpH = h0b;  const short* hpL = lo0;  long sHp = 0;
    short* oHi = hiA; short* oLo = loA;
    for (int i = 0; i < L; i++) {
        const int* es = (i == 0) ? iEsrc0 : iEsrc;
        gemm_gru_mfma_k<<<dim3(gx64, 1, 4), 512, 0, stream>>>(
            hin, hpH, hpL, Bp + (long)i * 131072, bp, oHi, oLo, iOff, es,
            N, NH, sHb, sHp);
        hpH = oHi; hpL = oLo; sHp = NH;
        hin = oHi; sHb = NH;
        if (oHi == hiA) { oHi = hiB; oLo = loB; }
        else            { oHi = hiA; oLo = loA; }
    }
    // final state: hiB + loB

    // ---- attention (MFMA) + fused vLN/residual/attention + pool + MLP ----
    gemm_mfma_k<1><<<gx64, 256, 0, stream>>>(h0, qwHi, qwLo, q_b, qbuf, N, 128);
    gemm_mfma_k<0><<<gx64, 256, 0, stream>>>(qbuf, kwHi, kwLo, nullptr, ubuf, N, 128);
    fusion_k<<<rb, 256, 0, stream>>>(hiB, loB, h0, qbuf, ubuf, k_b,
                                     vln_w, vln_b, fused, N);
    pool_k<<<64, 256, 0, stream>>>(fused, batch, poolMean, poolMax, N);
    classifier_k<<<64, 256, 0, stream>>>(
        poolMean, poolMax, c1w, c1b, c2w, c2b, c3w, c3b, out);
}